// Round 4
// baseline (623.479 us; speedup 1.0000x reference)
//
#include <hip/hip_runtime.h>
#include <stdint.h>

#define B_ 2
#define M_ 4096
#define N_ 4096
#define K_ 4096
#define KP 32    // uint4 units per packed row (K/128)
#define NCH 8    // K chunks
#define CP 4     // uint4 per row per chunk
#define TM 128
#define TN 128

typedef __attribute__((address_space(3))) uint32_t lds_u32;
typedef const __attribute__((address_space(1))) uint32_t glob_u32;

__device__ __forceinline__ void load_lds16(const uint4* g, uint4* l) {
    __builtin_amdgcn_global_load_lds((glob_u32*)g, (lds_u32*)l, 16, 0, 0);
}

// ---------------- pack ----------------
// Half-wave (32 lanes) packs one row (4096 floats -> 128 u32 words).
// Word w = l*4+c, bit j = NEGATIVE-sign of f[(j*32+l)*4+c]. Fixed within-row
// K-permutation, identical for x and y; complementing both operands leaves
// popcount(a^b) unchanged, so dots match the reference exactly.
__global__ __launch_bounds__(256) void pack_rows(
    const float* __restrict__ x, const float* __restrict__ y,
    uint32_t* __restrict__ px, uint32_t* __restrict__ py) {
    const float* in = blockIdx.y ? y : x;
    uint32_t* out   = blockIdx.y ? py : px;
    const int wid  = (blockIdx.x * blockDim.x + threadIdx.x) >> 6;  // 0..4095
    const int half = (threadIdx.x >> 5) & 1;
    const int l    = threadIdx.x & 31;
    const int row  = wid * 2 + half;  // 0..8191
    const float4* src = (const float4*)(in + (size_t)row * K_);
    uint32_t r0 = 0, r1 = 0, r2 = 0, r3 = 0;
#pragma unroll 8
    for (int j = 0; j < 32; ++j) {
        float4 f = src[j * 32 + l];
        r0 = (r0 << 1) | (__float_as_uint(f.x) >> 31);
        r1 = (r1 << 1) | (__float_as_uint(f.y) >> 31);
        r2 = (r2 << 1) | (__float_as_uint(f.z) >> 31);
        r3 = (r3 << 1) | (__float_as_uint(f.w) >> 31);
    }
    ((uint4*)(out + (size_t)row * 128))[l] = make_uint4(r0, r1, r2, r3);
}

// ---------------- binary GEMM ----------------
// C = (K - 2*popcount(a XOR b)) * scale.  128x128 tile, 256 threads,
// 8x8 per thread (rows ty+16i, cols tx+16j).
// LDS layout [buf][row][p ^ (row&3)] (uint4): XOR swizzle applied on the
// GLOBAL source side so global_load_lds (wave-uniform base + lane*16) can
// stage it. B-reads 2-way (free), A-reads broadcast, staging coalesced.
__global__ __launch_bounds__(256, 4) void bgemm(
    const uint4* __restrict__ pa, const uint4* __restrict__ pb,
    float* __restrict__ out, const float* __restrict__ xclip,
    const float* __restrict__ yclip) {
    __shared__ uint4 As[2][TM][CP];
    __shared__ uint4 Bs[2][TN][CP];

    const int b  = blockIdx.z;
    const int m0 = blockIdx.x * TM;
    const int n0 = blockIdx.y * TN;
    const int t  = threadIdx.x;
    const int tx = t & 15;
    const int ty = t >> 4;
    const int wq   = t >> 6;   // wave 0..3
    const int lane = t & 63;

    const uint4* ga = pa + ((size_t)b * M_ + m0) * KP;
    const uint4* gb = pb + ((size_t)b * N_ + n0) * KP;

    // staging: wave wq, issue q in {0,1}: slot s = wq*128 + q*64 + lane
    // slot s -> LDS [s>>2][s&3]; content = global pair (s&3) ^ ((s>>2)&3)
    int srow[2], srcp[2];
#pragma unroll
    for (int q = 0; q < 2; ++q) {
        int s = wq * 128 + q * 64 + lane;
        srow[q] = s >> 2;
        srcp[q] = (s & 3) ^ (srow[q] & 3);
    }

    unsigned acc[8][8] = {};

#define STAGE(ko, buf)                                                        \
    {                                                                         \
        _Pragma("unroll") for (int q = 0; q < 2; ++q) {                       \
            load_lds16(ga + (size_t)srow[q] * KP + (ko) + srcp[q],            \
                       &As[buf][0][0] + wq * 128 + q * 64);                   \
            load_lds16(gb + (size_t)srow[q] * KP + (ko) + srcp[q],            \
                       &Bs[buf][0][0] + wq * 128 + q * 64);                   \
        }                                                                     \
    }

    STAGE(0, 0);
    __syncthreads();

    for (int c = 0; c < NCH; ++c) {
        const int buf = c & 1;
        if (c + 1 < NCH) STAGE((c + 1) * CP, buf ^ 1);
#pragma unroll
        for (int p = 0; p < CP; ++p) {
#pragma unroll
            for (int jh = 0; jh < 2; ++jh) {
                uint4 bv[4];
#pragma unroll
                for (int j = 0; j < 4; ++j) {
                    int r = tx + 16 * (jh * 4 + j);
                    bv[j] = Bs[buf][r][p ^ (r & 3)];
                }
#pragma unroll
                for (int i = 0; i < 8; ++i) {
                    int r = ty + 16 * i;
                    uint4 av = As[buf][r][p ^ (r & 3)];
#pragma unroll
                    for (int j = 0; j < 4; ++j) {
                        unsigned* a = &acc[i][jh * 4 + j];
                        *a += __popc(av.x ^ bv[j].x);
                        *a += __popc(av.y ^ bv[j].y);
                        *a += __popc(av.z ^ bv[j].z);
                        *a += __popc(av.w ^ bv[j].w);
                    }
                }
            }
        }
        __syncthreads();
    }

    const float scale = xclip[0] * yclip[0];
#pragma unroll
    for (int i = 0; i < 8; ++i) {
        int m = m0 + ty + 16 * i;
        float* orow = out + ((size_t)b * M_ + m) * (size_t)N_ + n0;
#pragma unroll
        for (int j = 0; j < 8; ++j) {
            int n = tx + 16 * j;
            orow[n] = scale * (float)(K_ - 2 * (int)acc[i][j]);
        }
    }
}

extern "C" void kernel_launch(void* const* d_in, const int* in_sizes, int n_in,
                              void* d_out, int out_size, void* d_ws, size_t ws_size,
                              hipStream_t stream) {
    const float* x     = (const float*)d_in[0];
    const float* y     = (const float*)d_in[1];
    const float* xclip = (const float*)d_in[2];
    const float* yclip = (const float*)d_in[3];
    float* out = (float*)d_out;

    uint32_t* pa = (uint32_t*)d_ws;                 // [B][M][128] u32 = 4 MB
    uint32_t* pb = pa + (size_t)B_ * M_ * 128;      // [B][N][128] u32 = 4 MB

    hipLaunchKernelGGL(pack_rows, dim3(1024, 2), dim3(256), 0, stream,
                       x, y, pa, pb);

    dim3 grid(M_ / TM, N_ / TN, B_);
    hipLaunchKernelGGL(bgemm, grid, dim3(256), 0, stream,
                       (const uint4*)pa, (const uint4*)pb, out, xclip, yclip);
}

// Round 5
// 440.500 us; speedup vs baseline: 1.4154x; 1.4154x over previous
//
#include <hip/hip_runtime.h>
#include <stdint.h>

#define B_ 2
#define M_ 4096
#define N_ 4096
#define K_ 4096
#define WPR 128        // u32 words per packed row (K/32)
#define NCH 64         // K chunks of 64 bits
#define TM 128
#define TN 128
#define LDR 80         // LDS row stride in bytes (64 data + 16 pad -> bank-uniform)

typedef int v4i  __attribute__((ext_vector_type(4)));
typedef int v16i __attribute__((ext_vector_type(16)));

// ---------------- pack + row popcounts ----------------
// Half-wave (32 lanes) packs one row (4096 floats -> 128 u32 words, bit =
// sign bit). Fixed within-row K-permutation, identical for x and y. Also
// reduces the row popcount (permutation-invariant) into rp[row].
__global__ __launch_bounds__(256) void pack_rows(
    const float* __restrict__ x, const float* __restrict__ y,
    uint32_t* __restrict__ px, uint32_t* __restrict__ py,
    int* __restrict__ rpx, int* __restrict__ rpy) {
    const float* in = blockIdx.y ? y : x;
    uint32_t* out   = blockIdx.y ? py : px;
    int* rp         = blockIdx.y ? rpy : rpx;
    const int wid  = (blockIdx.x * blockDim.x + threadIdx.x) >> 6;  // 0..4095
    const int half = (threadIdx.x >> 5) & 1;
    const int l    = threadIdx.x & 31;
    const int row  = wid * 2 + half;  // 0..8191
    const float4* src = (const float4*)(in + (size_t)row * K_);
    uint32_t r0 = 0, r1 = 0, r2 = 0, r3 = 0;
#pragma unroll 8
    for (int j = 0; j < 32; ++j) {
        float4 f = src[j * 32 + l];
        r0 = (r0 << 1) | (__float_as_uint(f.x) >> 31);
        r1 = (r1 << 1) | (__float_as_uint(f.y) >> 31);
        r2 = (r2 << 1) | (__float_as_uint(f.z) >> 31);
        r3 = (r3 << 1) | (__float_as_uint(f.w) >> 31);
    }
    ((uint4*)(out + (size_t)row * WPR))[l] = make_uint4(r0, r1, r2, r3);
    int p = __popc(r0) + __popc(r1) + __popc(r2) + __popc(r3);
#pragma unroll
    for (int off = 1; off < 32; off <<= 1) p += __shfl_xor(p, off);
    if (l == 0) rp[row] = p;
}

// ---------------- i8 MFMA binary GEMM ----------------
// S = (0/1 bits of A) . (0/1 bits of B)^T via v_mfma_i32_32x32x32_i8.
// out = scale * (K - 2*pa[m] - 2*pb[n] + 4*S).
// 128x128 tile, 4 waves, each wave 2x2 tiles of 32x32 (64x64 region).
// Per chunk (64 bits of K): each thread expands one u32 word of A and one of
// B into 32 {0,1} bytes (2 ops/dword) and writes 32 B to LDS; double-buffered,
// one barrier per chunk. LDS row pad 80 B -> uniform bank spread.
__global__ __launch_bounds__(256, 4) void bgemm_i8(
    const uint32_t* __restrict__ pxw, const uint32_t* __restrict__ pyw,
    const int* __restrict__ rpx, const int* __restrict__ rpy,
    float* __restrict__ out, const float* __restrict__ xclip,
    const float* __restrict__ yclip) {
    __shared__ uint8_t As[2][TM * LDR];
    __shared__ uint8_t Bs[2][TN * LDR];

    const int b    = blockIdx.z;
    const int m0   = blockIdx.x * TM;
    const int n0   = blockIdx.y * TN;
    const int t    = threadIdx.x;
    const int lane = t & 63;
    const int w    = t >> 6;
    const int wr   = w >> 1, wc = w & 1;

    // expansion source: row er = t>>1, word-half wh = t&1 (words 2c+wh)
    const int er = t >> 1;
    const int wh = t & 1;
    const uint32_t* gA = pxw + ((size_t)(b * M_ + m0 + er)) * WPR + wh;
    const uint32_t* gB = pyw + ((size_t)(b * N_ + n0 + er)) * WPR + wh;

    v16i acc[2][2];
#pragma unroll
    for (int ti = 0; ti < 2; ++ti)
#pragma unroll
        for (int tj = 0; tj < 2; ++tj)
#pragma unroll
            for (int r = 0; r < 16; ++r) acc[ti][tj][r] = 0;

    // expand word -> 32 bytes {0,1}: dword k byte j = bit (k + 8j)
#define EXPAND_STORE(wv, base)                                              \
    {                                                                       \
        uint32_t d0 = (wv)&0x01010101u, d1 = ((wv) >> 1) & 0x01010101u;     \
        uint32_t d2 = ((wv) >> 2) & 0x01010101u, d3 = ((wv) >> 3) & 0x01010101u; \
        uint32_t d4 = ((wv) >> 4) & 0x01010101u, d5 = ((wv) >> 5) & 0x01010101u; \
        uint32_t d6 = ((wv) >> 6) & 0x01010101u, d7 = ((wv) >> 7) & 0x01010101u; \
        uint4* p_ = (uint4*)((base) + er * LDR + wh * 32);                  \
        p_[0] = make_uint4(d0, d1, d2, d3);                                 \
        p_[1] = make_uint4(d4, d5, d6, d7);                                 \
    }

    uint32_t wa = gA[0], wb = gB[0];
    EXPAND_STORE(wa, As[0]);
    EXPAND_STORE(wb, Bs[0]);
    __syncthreads();

    for (int c = 0; c < NCH; ++c) {
        const int buf = c & 1;
        if (c + 1 < NCH) {  // prefetch next words (L2-hot, 8 MB footprint)
            wa = gA[2 * (c + 1)];
            wb = gB[2 * (c + 1)];
        }
#pragma unroll
        for (int ks = 0; ks < 2; ++ks) {
            v4i af[2], bf[2];
#pragma unroll
            for (int ti = 0; ti < 2; ++ti) {
                int r = wr * 64 + ti * 32 + (lane & 31);
                af[ti] = *(const v4i*)(&As[buf][r * LDR + ks * 32 + (lane >> 5) * 16]);
            }
#pragma unroll
            for (int tj = 0; tj < 2; ++tj) {
                int r = wc * 64 + tj * 32 + (lane & 31);
                bf[tj] = *(const v4i*)(&Bs[buf][r * LDR + ks * 32 + (lane >> 5) * 16]);
            }
#pragma unroll
            for (int ti = 0; ti < 2; ++ti)
#pragma unroll
                for (int tj = 0; tj < 2; ++tj)
                    acc[ti][tj] = __builtin_amdgcn_mfma_i32_32x32x32_i8(
                        af[ti], bf[tj], acc[ti][tj], 0, 0, 0);
        }
        if (c + 1 < NCH) {
            EXPAND_STORE(wa, As[buf ^ 1]);
            EXPAND_STORE(wb, Bs[buf ^ 1]);
        }
        __syncthreads();
    }

    // epilogue: C/D layout (32x32): col = lane&31, row = (r&3)+8*(r>>2)+4*(lane>>5)
    const float scale = xclip[0] * yclip[0];
    const int col   = lane & 31;
    const int rquad = (lane >> 5) * 4;
#pragma unroll
    for (int ti = 0; ti < 2; ++ti) {
#pragma unroll
        for (int r = 0; r < 16; ++r) {
            int rowl = (r & 3) + 8 * (r >> 2) + rquad;
            int mm = m0 + wr * 64 + ti * 32 + rowl;
            int pav = rpx[b * M_ + mm];
            float* orow = out + ((size_t)b * M_ + mm) * (size_t)N_;
#pragma unroll
            for (int tj = 0; tj < 2; ++tj) {
                int nn = n0 + wc * 64 + tj * 32 + col;
                int pbv = rpy[b * N_ + nn];
                int ci = K_ - 2 * (pav + pbv) + 4 * acc[ti][tj][r];
                orow[nn] = scale * (float)ci;
            }
        }
    }
}

extern "C" void kernel_launch(void* const* d_in, const int* in_sizes, int n_in,
                              void* d_out, int out_size, void* d_ws, size_t ws_size,
                              hipStream_t stream) {
    const float* x     = (const float*)d_in[0];
    const float* y     = (const float*)d_in[1];
    const float* xclip = (const float*)d_in[2];
    const float* yclip = (const float*)d_in[3];
    float* out = (float*)d_out;

    // workspace: px 4MB | py 4MB | rpx 32KB | rpy 32KB  (requires ws >= 8.1MB)
    uint32_t* px = (uint32_t*)d_ws;
    uint32_t* py = px + (size_t)B_ * M_ * WPR;
    int* rpx = (int*)(py + (size_t)B_ * N_ * WPR);
    int* rpy = rpx + B_ * M_;

    hipLaunchKernelGGL(pack_rows, dim3(1024, 2), dim3(256), 0, stream,
                       x, y, px, py, rpx, rpy);

    dim3 grid(M_ / TM, N_ / TN, B_);
    hipLaunchKernelGGL(bgemm_i8, grid, dim3(256), 0, stream,
                       px, py, rpx, rpy, out, xclip, yclip);
}